// Round 7
// baseline (488.929 us; speedup 1.0000x reference)
//
#include <hip/hip_runtime.h>
#include <hip/hip_bf16.h>

// Problem constants (fixed by reference): N=262144 rows, D=64, K=512 codes.
#define N_ROWS 262144
#define DIM 64
#define KC 512

// d_out layout — FLOAT32 (confirmed R2/R3):
//   out[0]                      = loss
//   out[1 .. 1+N*D)             = quantized [N,64] row-major
//   out[1+N*D .. 1+N*D+N)       = float(encoding_indices)
//
// CORRECTNESS INVARIANT (hard-won, R2..R6): the reference argmin is over
// FLOAT32 distances; near-ties are decided by the reference's own f32
// rounding. Replicate its numerics EXACTLY and decide in f32:
//   x_sq, e_sq : numpy pairwise sum (8-acc striped, squares rounded
//                separately, no FMA)
//   dot        : sequential fused-FMA chain, k ascending
//   d          : fl( fl(x_sq + e_sq_k) - 2*dot_k ), contraction off
//   argmin     : strict <, first-min-wins
// *** NO f64 override anywhere. *** Every version with an f64 "safety net"
// on near-ties (R2/R4/R5/R6) failed with identical absmax 464.0 — the f64
// truth disagrees with the f32 reference on exactly those rows. R3 (pure
// f32 replication) passed at absmax 7.6e-6.

// numpy pairwise sum of squares for n=64 — bit-exact vs np (proven R3).
__device__ __forceinline__ float np_sumsq64(const float* a) {
#pragma clang fp contract(off)
    float r[8];
#pragma unroll
    for (int j = 0; j < 8; ++j) r[j] = a[j] * a[j];
#pragma unroll
    for (int i = 8; i < 64; i += 8)
#pragma unroll
        for (int j = 0; j < 8; ++j) r[j] = r[j] + a[i + j] * a[i + j];
    return ((r[0] + r[1]) + (r[2] + r[3])) + ((r[4] + r[5]) + (r[6] + r[7]));
}

// ---- kernel 1: e_sq_k with numpy bit-exact summation ----
__global__ void esq_kernel(const float* __restrict__ cb, float* __restrict__ esq) {
    int k = blockIdx.x * blockDim.x + threadIdx.x;
    if (k < KC) esq[k] = np_sumsq64(cb + k * DIM);
}

// ---- kernel 2: main VQ — one thread per row, row register-resident ----
// launch_bounds(256,4): 128-VGPR budget. With the f64 cold path gone there
// is no dynamic indexing into xr[] anywhere, so the row lives in VGPRs
// (R3's VGPR=40 / WRITE_SIZE=305MB scratch spill is the 2.3x we're buying
// back; this kernel changes NO arithmetic vs R3).
__global__ __launch_bounds__(256, 4) void vq_kernel(
    const float* __restrict__ x, const float* __restrict__ cb,
    const float* __restrict__ esq, float* __restrict__ out,
    float* __restrict__ loss_acc)
{
    const int row = blockIdx.x * 256 + threadIdx.x;
    if (row >= N_ROWS) return;

    // Row into 64 VGPRs (16x float4, statically indexed only).
    float xr[DIM];
    const float4* xv = reinterpret_cast<const float4*>(x + (size_t)row * DIM);
#pragma unroll
    for (int j = 0; j < DIM / 4; ++j) {
        float4 v = xv[j];
        xr[4 * j + 0] = v.x; xr[4 * j + 1] = v.y;
        xr[4 * j + 2] = v.z; xr[4 * j + 3] = v.w;
    }

    // numpy-exact ||x||^2.
    const float xsq = np_sumsq64(xr);

    // Replicated reference distance; strict-< first-min-wins. unroll 2 gives
    // two independent fmaf chains (per-chain order unchanged) for latency.
    float best = 3.4e38f;
    int bidx = 0;
#pragma unroll 2
    for (int k = 0; k < KC; ++k) {
        const float* e = cb + k * DIM;   // wave-uniform -> scalar loads
        float dot = 0.f;
#pragma unroll
        for (int j = 0; j < DIM; ++j) dot = fmaf(xr[j], e[j], dot);
        float d;
        {
#pragma clang fp contract(off)
            float t1 = xsq + esq[k];     // rounds (ufunc pass 1)
            d = t1 - 2.0f * dot;         // 2*dot exact; subtract rounds
        }
        if (d < best) { best = d; bidx = k; }
    }

    // quantized = codebook[bidx]
    const float* eb = cb + (size_t)bidx * DIM;
    float* q = out + 1 + (size_t)row * DIM;
#pragma unroll
    for (int j = 0; j < DIM; ++j) q[j] = eb[j];

    out[1 + (size_t)N_ROWS * DIM + row] = (float)bidx;

    // loss contribution: ||x - e||^2 = d_best
    float lrow = best;
#pragma unroll
    for (int off = 32; off > 0; off >>= 1) lrow += __shfl_down(lrow, off, 64);
    if ((threadIdx.x & 63) == 0) atomicAdd(loss_acc, lrow);
}

// ---- kernel 3: finalize loss ----
__global__ void fin_kernel(const float* __restrict__ loss_acc,
                           float* __restrict__ out) {
    if (threadIdx.x == 0) {
        float mean_sq = (*loss_acc) / (float)((size_t)N_ROWS * DIM);
        out[0] = 1.25f * mean_sq;  // q_loss + COMMITMENT_COST * e_loss
    }
}

extern "C" void kernel_launch(void* const* d_in, const int* in_sizes, int n_in,
                              void* d_out, int out_size, void* d_ws, size_t ws_size,
                              hipStream_t stream) {
    const float* x  = (const float*)d_in[0];
    const float* cb = (const float*)d_in[1];
    float* out = (float*)d_out;

    float* loss_acc = (float*)d_ws;                 // 4 B
    float* esq      = (float*)((char*)d_ws + 256);  // 512 f32 (2304 B total)

    hipMemsetAsync(d_ws, 0, 4, stream);             // zero loss accumulator
    esq_kernel<<<2, 256, 0, stream>>>(cb, esq);
    vq_kernel<<<N_ROWS / 256, 256, 0, stream>>>(x, cb, esq, out, loss_acc);
    fin_kernel<<<1, 64, 0, stream>>>(loss_acc, out);
}